// Round 6
// baseline (1022.200 us; speedup 1.0000x reference)
//
#include <hip/hip_runtime.h>
#include <stdint.h>

#define N_TOK 8192
#define DDIM  1024
#define NEXP  16
#define HDIM  1024
#define SHDIM 2048
#define TM 128
#define BK 64
#define MT_R 144       // max routed m-tiles: 16384 + 15*127 padded -> <= 18432 rows

// gateup merged grid (GEMM part)
#define SH_GU_NT  32
#define SH_GU_WGS 2048                 // 64 mt * 32 nt
#define RT_GU_NT  16
#define RT_GU_WGS 2304                 // 144 mt * 16 nt
#define GU_WGS    4352
#define GU_SLOTS  (GU_WGS / 8)         // 544 per XCD
// transpose riders in the gateup launch: Wd (4096 tiles) + sWd (512 tiles)
#define TR2_WGS   4608
#define TR2_SLOTS (TR2_WGS / 8)        // 576 per XCD
#define GUF_WGS   (GU_WGS + TR2_WGS)   // 8960

#define TND 128
#define DN_WGS    1664                 // 512 shared + 1152 routed

// launch 3: gate/up weight transposes + assign
#define TR1_WGS   9216                 // Wg 4096 + Wu 4096 + sWg 512 + sWu 512
#define ASG_WGS   64
#define T1A_WGS   (TR1_WGS + ASG_WGS)  // 9280

#define CPAD 16   // counter padding: one 64B line per counter

typedef __bf16 bf16x8 __attribute__((ext_vector_type(8)));
typedef float  f32x4  __attribute__((ext_vector_type(4)));

__device__ __forceinline__ unsigned short f2bf(float f) {
  union { float f; unsigned u; } v; v.f = f;
  unsigned r = v.u + 0x7fffu + ((v.u >> 16) & 1u);
  return (unsigned short)(r >> 16);
}
__device__ __forceinline__ float bf2f(unsigned short u) {
  union { unsigned u; float f; } v; v.u = (unsigned)u << 16; return v.f;
}

__device__ __forceinline__ void gload16(const void* g, void* l) {
  __builtin_amdgcn_global_load_lds(
      (const __attribute__((address_space(1))) void*)g,
      (__attribute__((address_space(3))) void*)l, 16, 0, 0);
}

// XCD-aware bijective block swizzle (requires gridDim.x % 8 == 0).
__device__ __forceinline__ int xcd_swizzle() {
  int nwg = (int)gridDim.x;
  int b = (int)blockIdx.x;
  return (b & 7) * (nwg >> 3) + (b >> 3);
}

// padded per-expert segment offsets computed from cnt (replaces k_prefix)
__device__ __forceinline__ void calc_offs(const int* __restrict__ cnt, int* offs) {
  int o = 0;
#pragma unroll
  for (int e = 0; e < NEXP; e++) { offs[e] = o; o += ((cnt[e * CPAD] + 127) & ~127); }
  offs[NEXP] = o;
}

// ---------------- small setup kernels ----------------

__global__ void k_zero(int* cnt, int* cursor, float* probsum) {
  int t = threadIdx.x;
  if (t < NEXP * CPAD) { cnt[t] = 0; cursor[t] = 0; probsum[t] = 0.f; }
}

// 512 blocks x 256 threads; 16 tokens/block (4 per wave).
// Emits Xbf, top-2 routing, cnt atomics, and block-reduced probsum.
__global__ __launch_bounds__(256) void k_router(
    const float* __restrict__ x, const float* __restrict__ rw,
    const float* __restrict__ rb, int* __restrict__ cnt,
    int* __restrict__ tok_idx, float* __restrict__ tok_w,
    float* __restrict__ probsum, unsigned short* __restrict__ Xbf) {
  __shared__ float rwT[NEXP * 1024];
  __shared__ float ps[NEXP];
  const int t = threadIdx.x;
  if (t < NEXP) ps[t] = 0.f;
  {
    int dbase = t >> 2, e0 = (t & 3) * 4;
#pragma unroll
    for (int c = 0; c < 16; c++) {
      int d = dbase + 64 * c;
      float4 v = *(const float4*)(rw + (size_t)d * NEXP + e0);
      rwT[(e0 + 0) * 1024 + d] = v.x;
      rwT[(e0 + 1) * 1024 + d] = v.y;
      rwT[(e0 + 2) * 1024 + d] = v.z;
      rwT[(e0 + 3) * 1024 + d] = v.w;
    }
  }
  __syncthreads();
  const int lane = t & 63, wv = t >> 6;
  const int tok0 = blockIdx.x * 16 + wv * 4;
  float acc[4][NEXP];
#pragma unroll
  for (int tt = 0; tt < 4; tt++)
#pragma unroll
    for (int e = 0; e < NEXP; e++) acc[tt][e] = 0.f;

#pragma unroll
  for (int c = 0; c < 4; c++) {
    int d = lane * 4 + 256 * c;
    float4 xv[4];
#pragma unroll
    for (int tt = 0; tt < 4; tt++) {
      xv[tt] = *(const float4*)(x + (size_t)(tok0 + tt) * DDIM + d);
      ushort4 o;
      o.x = f2bf(xv[tt].x); o.y = f2bf(xv[tt].y);
      o.z = f2bf(xv[tt].z); o.w = f2bf(xv[tt].w);
      *(ushort4*)(Xbf + (size_t)(tok0 + tt) * DDIM + d) = o;
    }
#pragma unroll
    for (int e = 0; e < NEXP; e++) {
      float4 w4 = *(const float4*)(&rwT[e * 1024 + d]);
#pragma unroll
      for (int tt = 0; tt < 4; tt++) {
        acc[tt][e] = fmaf(xv[tt].x, w4.x, acc[tt][e]);
        acc[tt][e] = fmaf(xv[tt].y, w4.y, acc[tt][e]);
        acc[tt][e] = fmaf(xv[tt].z, w4.z, acc[tt][e]);
        acc[tt][e] = fmaf(xv[tt].w, w4.w, acc[tt][e]);
      }
    }
  }
#pragma unroll
  for (int tt = 0; tt < 4; tt++)
#pragma unroll
    for (int e = 0; e < NEXP; e++) {
      float v = acc[tt][e];
#pragma unroll
      for (int o = 32; o; o >>= 1) v += __shfl_xor(v, o);
      acc[tt][e] = v;
    }

#pragma unroll
  for (int tt = 0; tt < 4; tt++) {
    if (lane == tt) {
      int tok = tok0 + tt;
      float mx = acc[tt][0];
#pragma unroll
      for (int e = 1; e < NEXP; e++) mx = fmaxf(mx, acc[tt][e]);
      float p[NEXP]; float s = 0.f;
#pragma unroll
      for (int e = 0; e < NEXP; e++) { p[e] = __expf(acc[tt][e] - mx); s += p[e]; }
      float inv = 1.f / s;
#pragma unroll
      for (int e = 0; e < NEXP; e++) { p[e] *= inv; atomicAdd(&ps[e], p[e]); }
      int i0 = 0; float b0 = acc[tt][0] + rb[0];
#pragma unroll
      for (int e = 1; e < NEXP; e++) { float v = acc[tt][e] + rb[e]; if (v > b0) { b0 = v; i0 = e; } }
      int i1 = -1; float b1 = -3.4e38f;
#pragma unroll
      for (int e = 0; e < NEXP; e++) {
        if (e == i0) continue;
        float v = acc[tt][e] + rb[e]; if (v > b1) { b1 = v; i1 = e; }
      }
      float w0 = 0.f, w1 = 0.f;
#pragma unroll
      for (int e = 0; e < NEXP; e++) { if (e == i0) w0 = p[e]; if (e == i1) w1 = p[e]; }
      float ssum = fmaxf(w0 + w1, 1e-9f);
      w0 /= ssum; w1 /= ssum;
      atomicAdd(&cnt[i0 * CPAD], 1); atomicAdd(&cnt[i1 * CPAD], 1);
      tok_idx[tok * 2]     = i0; tok_idx[tok * 2 + 1] = i1;
      tok_w[tok * 2]       = w0; tok_w[tok * 2 + 1]   = w1;
    }
  }
  __syncthreads();
  if (t < NEXP) atomicAdd(&probsum[t * CPAD], ps[t]);
}

// ---------------- transpose helper (fp32 [R][C] -> bf16 [C][R]) ----------------

__device__ __forceinline__ void do_transpose64(
    const float* __restrict__ src, unsigned short* __restrict__ dst,
    int R, int C, int tc, int tr, float* tile /* 64*65 */) {
  int rx = threadIdx.x >> 4;
  int cx = (threadIdx.x & 15) * 4;
#pragma unroll
  for (int p = 0; p < 4; p++) {
    int r = p * 16 + rx;
    float4 v = *(const float4*)(src + (size_t)(tr + r) * C + tc + cx);
    tile[(cx + 0) * 65 + r] = v.x;
    tile[(cx + 1) * 65 + r] = v.y;
    tile[(cx + 2) * 65 + r] = v.z;
    tile[(cx + 3) * 65 + r] = v.w;
  }
  __syncthreads();
#pragma unroll
  for (int p = 0; p < 4; p++) {
    int c = p * 16 + rx;
    float v0 = tile[c * 65 + cx + 0];
    float v1 = tile[c * 65 + cx + 1];
    float v2 = tile[c * 65 + cx + 2];
    float v3 = tile[c * 65 + cx + 3];
    ushort4 o; o.x = f2bf(v0); o.y = f2bf(v1); o.z = f2bf(v2); o.w = f2bf(v3);
    *(ushort4*)(dst + (size_t)(tc + c) * R + tr + cx) = o;
  }
}

// launch 3: gate/up weight transposes (9216 blocks) + routed-row assign (64 blocks)
__global__ __launch_bounds__(256) void k_trgu_assign(
    const float* __restrict__ Wg, const float* __restrict__ Wu,
    const float* __restrict__ sWg, const float* __restrict__ sWu,
    unsigned short* __restrict__ WgT, unsigned short* __restrict__ WuT,
    unsigned short* __restrict__ sWgT, unsigned short* __restrict__ sWuT,
    const int* __restrict__ tok_idx, int* __restrict__ cursor,
    const int* __restrict__ cnt, int* __restrict__ row_token,
    int* __restrict__ tok_rows) {
  __shared__ float tile[64 * 65];
  int id = blockIdx.x;
  if (id < 4096) {
    int mat = id >> 8, tl = id & 255;
    do_transpose64(Wg + ((size_t)mat << 20), WgT + ((size_t)mat << 20),
                   1024, 1024, (tl & 15) * 64, (tl >> 4) * 64, tile);
  } else if (id < 8192) {
    int mat = (id - 4096) >> 8, tl = id & 255;
    do_transpose64(Wu + ((size_t)mat << 20), WuT + ((size_t)mat << 20),
                   1024, 1024, (tl & 15) * 64, (tl >> 4) * 64, tile);
  } else if (id < 8704) {
    int tl = id - 8192;
    do_transpose64(sWg, sWgT, 1024, 2048, (tl & 31) * 64, (tl >> 5) * 64, tile);
  } else if (id < TR1_WGS) {
    int tl = id - 8704;
    do_transpose64(sWu, sWuT, 1024, 2048, (tl & 31) * 64, (tl >> 5) * 64, tile);
  } else {
    int i = (id - TR1_WGS) * 256 + threadIdx.x;   // [0, 16384)
    int offs[NEXP + 1];
    calc_offs(cnt, offs);
    int e = tok_idx[i];
    int pos = atomicAdd(&cursor[e * CPAD], 1);
    int row = offs[e] + pos;
    row_token[row] = i >> 1;
    tok_rows[i] = row;
  }
}

// ---------------- merged GEMM kernels (m97 structure) ----------------
// Single-buffered 32KB LDS, 2-barrier K-loop, global_load_lds width 16,
// 16B-unit XOR swizzle, per-XCD slot split: GEMM slots first (banded tile
// order), then Wd/sWd transpose riders that soak idle HBM BW.

__global__ __launch_bounds__(256, 5) void k_gateup_all(
    const unsigned short* __restrict__ Xbf,
    const unsigned short* __restrict__ sWgT,
    const unsigned short* __restrict__ sWuT,
    const unsigned short* __restrict__ WgT,
    const unsigned short* __restrict__ WuT,
    unsigned short* __restrict__ Hs,
    unsigned short* __restrict__ Hr,
    const int* __restrict__ cnt,
    const int* __restrict__ row_token,
    const float* __restrict__ Wd, const float* __restrict__ sWd,
    unsigned short* __restrict__ WdT, unsigned short* __restrict__ sWdT) {
  __shared__ __attribute__((aligned(16))) char smem[32768];
  unsigned short* As  = (unsigned short*)smem;             // 16 KB
  unsigned short* Bgs = (unsigned short*)(smem + 16384);   //  8 KB
  unsigned short* Bus = (unsigned short*)(smem + 24576);   //  8 KB

  const int slot = blockIdx.x >> 3;
  const int xcd  = blockIdx.x & 7;

  if (slot >= GU_SLOTS) {
    // transpose riders: Wd (4096 tiles) then sWd (512)
    int tid = xcd * TR2_SLOTS + (slot - GU_SLOTS);
    float* tile = (float*)smem;
    if (tid < 4096) {
      int mat = tid >> 8, tl = tid & 255;
      do_transpose64(Wd + ((size_t)mat << 20), WdT + ((size_t)mat << 20),
                     1024, 1024, (tl & 15) * 64, (tl >> 4) * 64, tile);
    } else {
      int tl = tid - 4096;
      do_transpose64(sWd, sWdT, 2048, 1024, (tl & 15) * 64, (tl >> 4) * 64, tile);
    }
    return;
  }

  const int wg = xcd * GU_SLOTS + slot;   // [0, 4352), contiguous per XCD
  const int t = threadIdx.x;
  const int lane = t & 63, wv = t >> 6;
  const int lr  = lane >> 3;            // row within 8-row chunk
  const int kbx = (lane & 7) ^ lr;      // pre-swizzled 16B-unit column

  int tm, tn, validEnd, Nh;
  const unsigned short *Bgp, *Bup;
  unsigned short* Hout;
  const unsigned short* pA[4];

  if (wg < SH_GU_WGS) {
    // banded decode: band of 8 nt, mt fastest inside
    int band = wg >> 9;
    int r = wg & 511;
    tm = (r >> 3) * TM;
    tn = (band * 8 + (r & 7)) * 64;
    validEnd = 0x7fffffff;
    Bgp = sWgT; Bup = sWuT;
    Hout = Hs; Nh = SHDIM;
#pragma unroll
    for (int j = 0; j < 4; j++)
      pA[j] = Xbf + (size_t)(tm + (wv * 4 + j) * 8 + lr) * DDIM;
  } else {
    int u = wg - SH_GU_WGS;
    int band = u / 1152;
    int r = u % 1152;
    tm = (r >> 3) * TM;
    tn = (band * 8 + (r & 7)) * 64;
    int offs[NEXP + 1];
    calc_offs(cnt, offs);
    if (tm >= offs[NEXP]) return;
    int e = 0;
#pragma unroll
    for (int i = 1; i < NEXP; i++) if (tm >= offs[i]) e = i;
    validEnd = offs[e] + cnt[e * CPAD];
    Bgp = WgT + (size_t)e * HDIM * DDIM;
    Bup = WuT + (size_t)e * HDIM * DDIM;
    Hout = Hr; Nh = HDIM;
#pragma unroll
    for (int j = 0; j < 4; j++) {
      int row = tm + (wv * 4 + j) * 8 + lr;
      int tok = row < validEnd ? row_token[row] : 0;
      pA[j] = Xbf + (size_t)tok * DDIM;
    }
  }
  const unsigned short* pBg[2];
  const unsigned short* pBu[2];
#pragma unroll
  for (int j = 0; j < 2; j++) {
    int row = tn + (wv * 2 + j) * 8 + lr;
    pBg[j] = Bgp + (size_t)row * DDIM;
    pBu[j] = Bup + (size_t)row * DDIM;
  }

  auto stage = [&](int k0) {
#pragma unroll
    for (int j = 0; j < 4; j++)
      gload16(pA[j] + k0 + kbx * 8, (void*)&As[(wv * 4 + j) * 512]);
#pragma unroll
    for (int j = 0; j < 2; j++) {
      gload16(pBg[j] + k0 + kbx * 8, (void*)&Bgs[(wv * 2 + j) * 512]);
      gload16(pBu[j] + k0 + kbx * 8, (void*)&Bus[(wv * 2 + j) * 512]);
    }
  };

  f32x4 accG[4][2] = {};
  f32x4 accU[4][2] = {};
  const int wr = wv >> 1, wc = wv & 1;
  const int rbase = lane & 15;
  const int kgrp = lane >> 4;

  for (int k0 = 0; k0 < DDIM; k0 += BK) {
    if (k0) __syncthreads();
    stage(k0);
    __syncthreads();
#pragma unroll
    for (int kk = 0; kk < 2; kk++) {
      bf16x8 af[4], gf[2], uf[2];
      int kbl = kk * 4 + kgrp;
#pragma unroll
      for (int i = 0; i < 4; i++) {
        int r = wr * 64 + i * 16 + rbase;
        af[i] = *(const bf16x8*)((const char*)As + r * 128 + ((kbl ^ (r & 7)) << 4));
      }
#pragma unroll
      for (int j = 0; j < 2; j++) {
        int r = wc * 32 + j * 16 + rbase;
        gf[j] = *(const bf16x8*)((const char*)Bgs + r * 128 + ((kbl ^ (r & 7)) << 4));
        uf[j] = *(const bf16x8*)((const char*)Bus + r * 128 + ((kbl ^ (r & 7)) << 4));
      }
#pragma unroll
      for (int i = 0; i < 4; i++)
#pragma unroll
        for (int j = 0; j < 2; j++) {
          accG[i][j] = __builtin_amdgcn_mfma_f32_16x16x32_bf16(af[i], gf[j], accG[i][j], 0, 0, 0);
          accU[i][j] = __builtin_amdgcn_mfma_f32_16x16x32_bf16(af[i], uf[j], accU[i][j], 0, 0, 0);
        }
    }
  }

  const int orow0 = tm + wr * 64 + (lane >> 4) * 4;
  const int ocol0 = tn + wc * 32 + (lane & 15);
#pragma unroll
  for (int i = 0; i < 4; i++)
#pragma unroll
    for (int j = 0; j < 2; j++)
#pragma unroll
      for (int r = 0; r < 4; r++) {
        int row = orow0 + i * 16 + r;
        if (row < validEnd) {
          float g = accG[i][j][r], u = accU[i][j][r];
          float h = g / (1.f + __expf(-g)) * u;
          Hout[(size_t)row * Nh + ocol0 + j * 16] = f2bf(h);
        }
      }
}

__global__ __launch_bounds__(256, 5) void k_down_all(
    const unsigned short* __restrict__ Hs,
    const unsigned short* __restrict__ Hr,
    const unsigned short* __restrict__ sWdT,
    const unsigned short* __restrict__ WdT,
    float* __restrict__ out,
    unsigned short* __restrict__ Rbuf,
    const int* __restrict__ cnt) {
  __shared__ unsigned short As[TM * BK];
  __shared__ unsigned short Bs[TND * BK];

  const int wg = xcd_swizzle();
  const int t = threadIdx.x;
  const int lane = t & 63, wv = t >> 6;
  const int lr  = lane >> 3;
  const int kbx = (lane & 7) ^ lr;

  int tm, tn, validEnd, K;
  bool routed;
  const unsigned short* pA[4];
  const unsigned short* pB[4];

  if (wg < 512) {
    routed = false; K = SHDIM;
    tm = (wg >> 3) * TM;
    tn = (wg & 7) * TND;
    validEnd = 0x7fffffff;
#pragma unroll
    for (int j = 0; j < 4; j++) {
      pA[j] = Hs + (size_t)(tm + (wv * 4 + j) * 8 + lr) * SHDIM;
      pB[j] = sWdT + (size_t)(tn + (wv * 4 + j) * 8 + lr) * SHDIM;
    }
  } else {
    routed = true; K = HDIM;
    int wgr = wg - 512;
    tm = (wgr >> 3) * TM;
    tn = (wgr & 7) * TND;
    int offs[NEXP + 1];
    calc_offs(cnt, offs);
    if (tm >= offs[NEXP]) return;
    int e = 0;
#pragma unroll
    for (int i = 1; i < NEXP; i++) if (tm >= offs[i]) e = i;
    validEnd = offs[e] + cnt[e * CPAD];
    const unsigned short* B = WdT + (size_t)e * DDIM * HDIM;
#pragma unroll
    for (int j = 0; j < 4; j++) {
      pA[j] = Hr + (size_t)(tm + (wv * 4 + j) * 8 + lr) * HDIM;
      pB[j] = B + (size_t)(tn + (wv * 4 + j) * 8 + lr) * HDIM;
    }
  }

  auto stage = [&](int k0) {
#pragma unroll
    for (int j = 0; j < 4; j++) {
      gload16(pA[j] + k0 + kbx * 8, (void*)&As[(wv * 4 + j) * 512]);
      gload16(pB[j] + k0 + kbx * 8, (void*)&Bs[(wv * 4 + j) * 512]);
    }
  };

  f32x4 acc[4][4] = {};
  const int wr = wv >> 1, wc = wv & 1;
  const int rbase = lane & 15;
  const int kgrp = lane >> 4;

  for (int k0 = 0; k0 < K; k0 += BK) {
    if (k0) __syncthreads();
    stage(k0);
    __syncthreads();
#pragma unroll
    for (int kk = 0; kk < 2; kk++) {
      bf16x8 af[4], bf[4];
      int kbl = kk * 4 + kgrp;
#pragma unroll
      for (int i = 0; i < 4; i++) {
        int r = wr * 64 + i * 16 + rbase;
        af[i] = *(const bf16x8*)((const char*)&As[0] + r * 128 + ((kbl ^ (r & 7)) << 4));
      }
#pragma unroll
      for (int j = 0; j < 4; j++) {
        int r = wc * 64 + j * 16 + rbase;
        bf[j] = *(const bf16x8*)((const char*)&Bs[0] + r * 128 + ((kbl ^ (r & 7)) << 4));
      }
#pragma unroll
      for (int i = 0; i < 4; i++)
#pragma unroll
        for (int j = 0; j < 4; j++)
          acc[i][j] = __builtin_amdgcn_mfma_f32_16x16x32_bf16(af[i], bf[j], acc[i][j], 0, 0, 0);
    }
  }

  const int orow0 = tm + wr * 64 + (lane >> 4) * 4;
  const int ocol0 = tn + wc * 64 + (lane & 15);
#pragma unroll
  for (int i = 0; i < 4; i++)
#pragma unroll
    for (int j = 0; j < 4; j++)
#pragma unroll
      for (int r = 0; r < 4; r++) {
        int row = orow0 + i * 16 + r;
        int col = ocol0 + j * 16;
        if (routed) {
          if (row < validEnd) Rbuf[(size_t)row * DDIM + col] = f2bf(acc[i][j][r]);
        } else {
          out[(size_t)row * DDIM + col] = acc[i][j][r];
        }
      }
}

// out[tok] += w0 * Rbuf[r0] + w1 * Rbuf[r1]; block 0 also writes the tail
__global__ __launch_bounds__(256) void k_combine(
    float* __restrict__ out, const unsigned short* __restrict__ Rbuf,
    const int* __restrict__ tok_rows, const float* __restrict__ tok_w,
    const float* __restrict__ probsum, const int* __restrict__ cnt,
    float* __restrict__ out_tail) {
  int tok = blockIdx.x;
  int c = threadIdx.x;
  int r0 = tok_rows[tok * 2], r1 = tok_rows[tok * 2 + 1];
  float w0 = tok_w[tok * 2],  w1 = tok_w[tok * 2 + 1];
  float4 o  = ((const float4*)(out + (size_t)tok * DDIM))[c];
  ushort4 a = ((const ushort4*)(Rbuf + (size_t)r0 * DDIM))[c];
  ushort4 b = ((const ushort4*)(Rbuf + (size_t)r1 * DDIM))[c];
  o.x += w0 * bf2f(a.x) + w1 * bf2f(b.x);
  o.y += w0 * bf2f(a.y) + w1 * bf2f(b.y);
  o.z += w0 * bf2f(a.z) + w1 * bf2f(b.z);
  o.w += w0 * bf2f(a.w) + w1 * bf2f(b.w);
  ((float4*)(out + (size_t)tok * DDIM))[c] = o;

  if (blockIdx.x == 0) {
    if (threadIdx.x == 0) {
      float bal = 0.f;
      for (int e = 0; e < NEXP; e++) {
        float frac = (float)cnt[e * CPAD] / (float)(N_TOK * 2);
        bal += frac * (probsum[e * CPAD] / (float)N_TOK);
      }
      out_tail[0] = 0.01f * (float)NEXP * bal;
    }
    if (threadIdx.x < NEXP) out_tail[1 + threadIdx.x] = (float)cnt[threadIdx.x * CPAD];
  }
}

// ---------------- launch ----------------

extern "C" void kernel_launch(void* const* d_in, const int* in_sizes, int n_in,
                              void* d_out, int out_size, void* d_ws, size_t ws_size,
                              hipStream_t stream) {
  const float* x   = (const float*)d_in[0];
  const float* rw  = (const float*)d_in[1];
  const float* rb  = (const float*)d_in[2];
  const float* Wg  = (const float*)d_in[3];
  const float* Wu  = (const float*)d_in[4];
  const float* Wd  = (const float*)d_in[5];
  const float* sWg = (const float*)d_in[6];
  const float* sWu = (const float*)d_in[7];
  const float* sWd = (const float*)d_in[8];
  float* out = (float*)d_out;

  uint8_t* w = (uint8_t*)d_ws;
  size_t off = 0;
  auto alloc = [&](size_t bytes) -> void* {
    void* p = w + off;
    off += (bytes + 255) & ~(size_t)255;
    return p;
  };

  int*   cnt      = (int*)alloc(NEXP * CPAD * 4);
  int*   cursor   = (int*)alloc(NEXP * CPAD * 4);
  float* probsum  = (float*)alloc(NEXP * CPAD * 4);
  int*   tok_idx  = (int*)alloc((size_t)N_TOK * 2 * 4);
  float* tok_w    = (float*)alloc((size_t)N_TOK * 2 * 4);
  int*   tok_rows = (int*)alloc((size_t)N_TOK * 2 * 4);
  int*   row_tok  = (int*)alloc((size_t)MT_R * TM * 4);
  unsigned short* Xbf  = (unsigned short*)alloc((size_t)N_TOK * DDIM * 2);
  unsigned short* Hs   = (unsigned short*)alloc((size_t)N_TOK * SHDIM * 2);
  unsigned short* Hr   = (unsigned short*)alloc((size_t)MT_R * TM * HDIM * 2);
  unsigned short* Rbuf = (unsigned short*)alloc((size_t)MT_R * TM * DDIM * 2);
  unsigned short* WgT  = (unsigned short*)alloc((size_t)NEXP * HDIM * DDIM * 2);
  unsigned short* WuT  = (unsigned short*)alloc((size_t)NEXP * HDIM * DDIM * 2);
  unsigned short* WdT  = (unsigned short*)alloc((size_t)NEXP * DDIM * HDIM * 2);
  unsigned short* sWgT = (unsigned short*)alloc((size_t)SHDIM * DDIM * 2);
  unsigned short* sWuT = (unsigned short*)alloc((size_t)SHDIM * DDIM * 2);
  unsigned short* sWdT = (unsigned short*)alloc((size_t)DDIM * SHDIM * 2);

  if (off > ws_size) return;

  k_zero<<<1, 256, 0, stream>>>(cnt, cursor, probsum);
  k_router<<<N_TOK / 16, 256, 0, stream>>>(x, rw, rb, cnt, tok_idx, tok_w, probsum, Xbf);
  k_trgu_assign<<<T1A_WGS, 256, 0, stream>>>(
      Wg, Wu, sWg, sWu, WgT, WuT, sWgT, sWuT,
      tok_idx, cursor, cnt, row_tok, tok_rows);
  k_gateup_all<<<GUF_WGS, 256, 0, stream>>>(
      Xbf, sWgT, sWuT, WgT, WuT, Hs, Hr, cnt, row_tok,
      Wd, sWd, WdT, sWdT);
  k_down_all<<<DN_WGS, 256, 0, stream>>>(
      Hs, Hr, sWdT, WdT, out, Rbuf, cnt);
  k_combine<<<N_TOK, 256, 0, stream>>>(
      out, Rbuf, tok_rows, tok_w, probsum, cnt, out + (size_t)N_TOK * DDIM);
}

// Round 7
// 405.054 us; speedup vs baseline: 2.5236x; 2.5236x over previous
//
#include <hip/hip_runtime.h>
#include <stdint.h>

#define N_TOK 8192
#define DDIM  1024
#define NEXP  16
#define HDIM  1024
#define SHDIM 2048
#define TM 128
#define BK 64
#define MT_R 144       // max routed m-tiles: 16384 + 15*127 padded -> <= 18432 rows

// gateup merged grid (GEMM part)
#define SH_GU_NT  32
#define SH_GU_WGS 2048                 // 64 mt * 32 nt
#define RT_GU_NT  16
#define RT_GU_WGS 2304                 // 144 mt * 16 nt
#define GU_WGS    4352
#define GU_SLOTS  (GU_WGS / 8)         // 544 per XCD
// transpose riders in the gateup launch: Wd (4096 tiles) + sWd (512 tiles)
#define TR2_WGS   4608
#define TR2_SLOTS (TR2_WGS / 8)        // 576 per XCD
#define GUF_WGS   (GU_WGS + TR2_WGS)   // 8960

#define TND 128
#define DN_WGS    1664                 // 512 shared + 1152 routed

// launch 3: gate/up weight transposes + assign
#define TR1_WGS   9216                 // Wg 4096 + Wu 4096 + sWg 512 + sWu 512
#define ASG_WGS   64
#define T1A_WGS   (TR1_WGS + ASG_WGS)  // 9280

#define CPAD 16   // counter padding: one 64B line per counter

typedef __bf16 bf16x8 __attribute__((ext_vector_type(8)));
typedef float  f32x4  __attribute__((ext_vector_type(4)));

__device__ __forceinline__ unsigned short f2bf(float f) {
  union { float f; unsigned u; } v; v.f = f;
  unsigned r = v.u + 0x7fffu + ((v.u >> 16) & 1u);
  return (unsigned short)(r >> 16);
}
__device__ __forceinline__ float bf2f(unsigned short u) {
  union { unsigned u; float f; } v; v.u = (unsigned)u << 16; return v.f;
}

__device__ __forceinline__ void gload16(const void* g, void* l) {
  __builtin_amdgcn_global_load_lds(
      (const __attribute__((address_space(1))) void*)g,
      (__attribute__((address_space(3))) void*)l, 16, 0, 0);
}

// XCD-aware bijective block swizzle (requires gridDim.x % 8 == 0).
__device__ __forceinline__ int xcd_swizzle() {
  int nwg = (int)gridDim.x;
  int b = (int)blockIdx.x;
  return (b & 7) * (nwg >> 3) + (b >> 3);
}

// Register-only segment lookup (NO local array -> no scratch, rule #20):
// finds expert e with offs[e] <= tm, its segment start and count, and total.
// Returns false if tm >= total padded rows.
__device__ __forceinline__ bool seg_lookup(const int* __restrict__ cnt, int tm,
                                           int& e, int& segStart, int& segCnt) {
  int o = 0; e = 0; segStart = 0; segCnt = 0;
#pragma unroll
  for (int i = 0; i < NEXP; i++) {
    int c = cnt[i * CPAD];
    if (tm >= o) { e = i; segStart = o; segCnt = c; }
    o += (c + 127) & ~127;
  }
  return tm < o;
}

// ---------------- small setup kernels ----------------

__global__ void k_zero(int* cnt, int* cursor, float* probsum) {
  int t = threadIdx.x;
  if (t < NEXP * CPAD) { cnt[t] = 0; cursor[t] = 0; probsum[t] = 0.f; }
}

// 512 blocks x 256 threads; 16 tokens/block (4 per wave).
// Emits Xbf, top-2 routing, cnt atomics, and block-reduced probsum.
__global__ __launch_bounds__(256) void k_router(
    const float* __restrict__ x, const float* __restrict__ rw,
    const float* __restrict__ rb, int* __restrict__ cnt,
    int* __restrict__ tok_idx, float* __restrict__ tok_w,
    float* __restrict__ probsum, unsigned short* __restrict__ Xbf) {
  __shared__ float rwT[NEXP * 1024];
  __shared__ float ps[NEXP];
  const int t = threadIdx.x;
  if (t < NEXP) ps[t] = 0.f;
  {
    int dbase = t >> 2, e0 = (t & 3) * 4;
#pragma unroll
    for (int c = 0; c < 16; c++) {
      int d = dbase + 64 * c;
      float4 v = *(const float4*)(rw + (size_t)d * NEXP + e0);
      rwT[(e0 + 0) * 1024 + d] = v.x;
      rwT[(e0 + 1) * 1024 + d] = v.y;
      rwT[(e0 + 2) * 1024 + d] = v.z;
      rwT[(e0 + 3) * 1024 + d] = v.w;
    }
  }
  __syncthreads();
  const int lane = t & 63, wv = t >> 6;
  const int tok0 = blockIdx.x * 16 + wv * 4;
  float acc[4][NEXP];
#pragma unroll
  for (int tt = 0; tt < 4; tt++)
#pragma unroll
    for (int e = 0; e < NEXP; e++) acc[tt][e] = 0.f;

#pragma unroll
  for (int c = 0; c < 4; c++) {
    int d = lane * 4 + 256 * c;
    float4 xv[4];
#pragma unroll
    for (int tt = 0; tt < 4; tt++) {
      xv[tt] = *(const float4*)(x + (size_t)(tok0 + tt) * DDIM + d);
      ushort4 o;
      o.x = f2bf(xv[tt].x); o.y = f2bf(xv[tt].y);
      o.z = f2bf(xv[tt].z); o.w = f2bf(xv[tt].w);
      *(ushort4*)(Xbf + (size_t)(tok0 + tt) * DDIM + d) = o;
    }
#pragma unroll
    for (int e = 0; e < NEXP; e++) {
      float4 w4 = *(const float4*)(&rwT[e * 1024 + d]);
#pragma unroll
      for (int tt = 0; tt < 4; tt++) {
        acc[tt][e] = fmaf(xv[tt].x, w4.x, acc[tt][e]);
        acc[tt][e] = fmaf(xv[tt].y, w4.y, acc[tt][e]);
        acc[tt][e] = fmaf(xv[tt].z, w4.z, acc[tt][e]);
        acc[tt][e] = fmaf(xv[tt].w, w4.w, acc[tt][e]);
      }
    }
  }
#pragma unroll
  for (int tt = 0; tt < 4; tt++)
#pragma unroll
    for (int e = 0; e < NEXP; e++) {
      float v = acc[tt][e];
#pragma unroll
      for (int o = 32; o; o >>= 1) v += __shfl_xor(v, o);
      acc[tt][e] = v;
    }

#pragma unroll
  for (int tt = 0; tt < 4; tt++) {
    if (lane == tt) {
      int tok = tok0 + tt;
      float mx = acc[tt][0];
#pragma unroll
      for (int e = 1; e < NEXP; e++) mx = fmaxf(mx, acc[tt][e]);
      float p[NEXP]; float s = 0.f;
#pragma unroll
      for (int e = 0; e < NEXP; e++) { p[e] = __expf(acc[tt][e] - mx); s += p[e]; }
      float inv = 1.f / s;
#pragma unroll
      for (int e = 0; e < NEXP; e++) { p[e] *= inv; atomicAdd(&ps[e], p[e]); }
      int i0 = 0; float b0 = acc[tt][0] + rb[0];
#pragma unroll
      for (int e = 1; e < NEXP; e++) { float v = acc[tt][e] + rb[e]; if (v > b0) { b0 = v; i0 = e; } }
      int i1 = -1; float b1 = -3.4e38f;
#pragma unroll
      for (int e = 0; e < NEXP; e++) {
        if (e == i0) continue;
        float v = acc[tt][e] + rb[e]; if (v > b1) { b1 = v; i1 = e; }
      }
      float w0 = 0.f, w1 = 0.f;
#pragma unroll
      for (int e = 0; e < NEXP; e++) { if (e == i0) w0 = p[e]; if (e == i1) w1 = p[e]; }
      float ssum = fmaxf(w0 + w1, 1e-9f);
      w0 /= ssum; w1 /= ssum;
      atomicAdd(&cnt[i0 * CPAD], 1); atomicAdd(&cnt[i1 * CPAD], 1);
      tok_idx[tok * 2]     = i0; tok_idx[tok * 2 + 1] = i1;
      tok_w[tok * 2]       = w0; tok_w[tok * 2 + 1]   = w1;
    }
  }
  __syncthreads();
  if (t < NEXP) atomicAdd(&probsum[t * CPAD], ps[t]);
}

// ---------------- transpose helper (fp32 [R][C] -> bf16 [C][R]) ----------------

__device__ __forceinline__ void do_transpose64(
    const float* __restrict__ src, unsigned short* __restrict__ dst,
    int R, int C, int tc, int tr, float* tile /* 64*65 */) {
  int rx = threadIdx.x >> 4;
  int cx = (threadIdx.x & 15) * 4;
#pragma unroll
  for (int p = 0; p < 4; p++) {
    int r = p * 16 + rx;
    float4 v = *(const float4*)(src + (size_t)(tr + r) * C + tc + cx);
    tile[(cx + 0) * 65 + r] = v.x;
    tile[(cx + 1) * 65 + r] = v.y;
    tile[(cx + 2) * 65 + r] = v.z;
    tile[(cx + 3) * 65 + r] = v.w;
  }
  __syncthreads();
#pragma unroll
  for (int p = 0; p < 4; p++) {
    int c = p * 16 + rx;
    float v0 = tile[c * 65 + cx + 0];
    float v1 = tile[c * 65 + cx + 1];
    float v2 = tile[c * 65 + cx + 2];
    float v3 = tile[c * 65 + cx + 3];
    ushort4 o; o.x = f2bf(v0); o.y = f2bf(v1); o.z = f2bf(v2); o.w = f2bf(v3);
    *(ushort4*)(dst + (size_t)(tc + c) * R + tr + cx) = o;
  }
}

// launch 3: gate/up weight transposes (9216 blocks) + routed-row assign (64 blocks)
__global__ __launch_bounds__(256) void k_trgu_assign(
    const float* __restrict__ Wg, const float* __restrict__ Wu,
    const float* __restrict__ sWg, const float* __restrict__ sWu,
    unsigned short* __restrict__ WgT, unsigned short* __restrict__ WuT,
    unsigned short* __restrict__ sWgT, unsigned short* __restrict__ sWuT,
    const int* __restrict__ tok_idx, int* __restrict__ cursor,
    const int* __restrict__ cnt, int* __restrict__ row_token,
    int* __restrict__ tok_rows) {
  __shared__ float tile[64 * 65];
  int id = blockIdx.x;
  if (id < 4096) {
    int mat = id >> 8, tl = id & 255;
    do_transpose64(Wg + ((size_t)mat << 20), WgT + ((size_t)mat << 20),
                   1024, 1024, (tl & 15) * 64, (tl >> 4) * 64, tile);
  } else if (id < 8192) {
    int mat = (id - 4096) >> 8, tl = id & 255;
    do_transpose64(Wu + ((size_t)mat << 20), WuT + ((size_t)mat << 20),
                   1024, 1024, (tl & 15) * 64, (tl >> 4) * 64, tile);
  } else if (id < 8704) {
    int tl = id - 8192;
    do_transpose64(sWg, sWgT, 1024, 2048, (tl & 31) * 64, (tl >> 5) * 64, tile);
  } else if (id < TR1_WGS) {
    int tl = id - 8704;
    do_transpose64(sWu, sWuT, 1024, 2048, (tl & 31) * 64, (tl >> 5) * 64, tile);
  } else {
    int i = (id - TR1_WGS) * 256 + threadIdx.x;   // [0, 16384)
    int e = tok_idx[i];
    // register-only offs[e]: scan with per-step compare (no local array)
    int o = 0, myoff = 0;
#pragma unroll
    for (int k = 0; k < NEXP; k++) {
      if (e == k) myoff = o;
      o += (cnt[k * CPAD] + 127) & ~127;
    }
    int pos = atomicAdd(&cursor[e * CPAD], 1);
    int row = myoff + pos;
    row_token[row] = i >> 1;
    tok_rows[i] = row;
  }
}

// ---------------- merged GEMM kernels (m97 structure) ----------------
// Single-buffered 32KB LDS, 2-barrier K-loop, global_load_lds width 16,
// 16B-unit XOR swizzle, per-XCD slot split: GEMM slots first (banded tile
// order), then Wd/sWd transpose riders that soak idle HBM BW.
// __launch_bounds__(256,4): cap=128 VGPR/wave fits 64 arch + 64 acc exactly;
// (256,5) capped at ~96 and spilled the accumulators (round-6 regression).

__global__ __launch_bounds__(256, 4) void k_gateup_all(
    const unsigned short* __restrict__ Xbf,
    const unsigned short* __restrict__ sWgT,
    const unsigned short* __restrict__ sWuT,
    const unsigned short* __restrict__ WgT,
    const unsigned short* __restrict__ WuT,
    unsigned short* __restrict__ Hs,
    unsigned short* __restrict__ Hr,
    const int* __restrict__ cnt,
    const int* __restrict__ row_token,
    const float* __restrict__ Wd, const float* __restrict__ sWd,
    unsigned short* __restrict__ WdT, unsigned short* __restrict__ sWdT) {
  __shared__ __attribute__((aligned(16))) char smem[32768];
  unsigned short* As  = (unsigned short*)smem;             // 16 KB
  unsigned short* Bgs = (unsigned short*)(smem + 16384);   //  8 KB
  unsigned short* Bus = (unsigned short*)(smem + 24576);   //  8 KB

  const int slot = blockIdx.x >> 3;
  const int xcd  = blockIdx.x & 7;

  if (slot >= GU_SLOTS) {
    // transpose riders: Wd (4096 tiles) then sWd (512)
    int tid = xcd * TR2_SLOTS + (slot - GU_SLOTS);
    float* tile = (float*)smem;
    if (tid < 4096) {
      int mat = tid >> 8, tl = tid & 255;
      do_transpose64(Wd + ((size_t)mat << 20), WdT + ((size_t)mat << 20),
                     1024, 1024, (tl & 15) * 64, (tl >> 4) * 64, tile);
    } else {
      int tl = tid - 4096;
      do_transpose64(sWd, sWdT, 2048, 1024, (tl & 15) * 64, (tl >> 4) * 64, tile);
    }
    return;
  }

  const int wg = xcd * GU_SLOTS + slot;   // [0, 4352), contiguous per XCD
  const int t = threadIdx.x;
  const int lane = t & 63, wv = t >> 6;
  const int lr  = lane >> 3;            // row within 8-row chunk
  const int kbx = (lane & 7) ^ lr;      // pre-swizzled 16B-unit column

  int tm, tn, validEnd, Nh;
  const unsigned short *Bgp, *Bup;
  unsigned short* Hout;
  const unsigned short* pA[4];

  if (wg < SH_GU_WGS) {
    // banded decode: band of 8 nt, mt fastest inside
    int band = wg >> 9;
    int r = wg & 511;
    tm = (r >> 3) * TM;
    tn = (band * 8 + (r & 7)) * 64;
    validEnd = 0x7fffffff;
    Bgp = sWgT; Bup = sWuT;
    Hout = Hs; Nh = SHDIM;
#pragma unroll
    for (int j = 0; j < 4; j++)
      pA[j] = Xbf + (size_t)(tm + (wv * 4 + j) * 8 + lr) * DDIM;
  } else {
    int u = wg - SH_GU_WGS;
    int band = u / 1152;
    int r = u % 1152;
    tm = (r >> 3) * TM;
    tn = (band * 8 + (r & 7)) * 64;
    int e, segStart, segCnt;
    if (!seg_lookup(cnt, tm, e, segStart, segCnt)) return;
    validEnd = segStart + segCnt;
    Bgp = WgT + (size_t)e * HDIM * DDIM;
    Bup = WuT + (size_t)e * HDIM * DDIM;
    Hout = Hr; Nh = HDIM;
#pragma unroll
    for (int j = 0; j < 4; j++) {
      int row = tm + (wv * 4 + j) * 8 + lr;
      int tok = row < validEnd ? row_token[row] : 0;
      pA[j] = Xbf + (size_t)tok * DDIM;
    }
  }
  const unsigned short* pBg[2];
  const unsigned short* pBu[2];
#pragma unroll
  for (int j = 0; j < 2; j++) {
    int row = tn + (wv * 2 + j) * 8 + lr;
    pBg[j] = Bgp + (size_t)row * DDIM;
    pBu[j] = Bup + (size_t)row * DDIM;
  }

  auto stage = [&](int k0) {
#pragma unroll
    for (int j = 0; j < 4; j++)
      gload16(pA[j] + k0 + kbx * 8, (void*)&As[(wv * 4 + j) * 512]);
#pragma unroll
    for (int j = 0; j < 2; j++) {
      gload16(pBg[j] + k0 + kbx * 8, (void*)&Bgs[(wv * 2 + j) * 512]);
      gload16(pBu[j] + k0 + kbx * 8, (void*)&Bus[(wv * 2 + j) * 512]);
    }
  };

  f32x4 accG[4][2] = {};
  f32x4 accU[4][2] = {};
  const int wr = wv >> 1, wc = wv & 1;
  const int rbase = lane & 15;
  const int kgrp = lane >> 4;

  for (int k0 = 0; k0 < DDIM; k0 += BK) {
    if (k0) __syncthreads();
    stage(k0);
    __syncthreads();
#pragma unroll
    for (int kk = 0; kk < 2; kk++) {
      bf16x8 af[4], gf[2], uf[2];
      int kbl = kk * 4 + kgrp;
#pragma unroll
      for (int i = 0; i < 4; i++) {
        int r = wr * 64 + i * 16 + rbase;
        af[i] = *(const bf16x8*)((const char*)As + r * 128 + ((kbl ^ (r & 7)) << 4));
      }
#pragma unroll
      for (int j = 0; j < 2; j++) {
        int r = wc * 32 + j * 16 + rbase;
        gf[j] = *(const bf16x8*)((const char*)Bgs + r * 128 + ((kbl ^ (r & 7)) << 4));
        uf[j] = *(const bf16x8*)((const char*)Bus + r * 128 + ((kbl ^ (r & 7)) << 4));
      }
#pragma unroll
      for (int i = 0; i < 4; i++)
#pragma unroll
        for (int j = 0; j < 2; j++) {
          accG[i][j] = __builtin_amdgcn_mfma_f32_16x16x32_bf16(af[i], gf[j], accG[i][j], 0, 0, 0);
          accU[i][j] = __builtin_amdgcn_mfma_f32_16x16x32_bf16(af[i], uf[j], accU[i][j], 0, 0, 0);
        }
    }
  }

  const int orow0 = tm + wr * 64 + (lane >> 4) * 4;
  const int ocol0 = tn + wc * 32 + (lane & 15);
#pragma unroll
  for (int i = 0; i < 4; i++)
#pragma unroll
    for (int j = 0; j < 2; j++)
#pragma unroll
      for (int r = 0; r < 4; r++) {
        int row = orow0 + i * 16 + r;
        if (row < validEnd) {
          float g = accG[i][j][r], u = accU[i][j][r];
          float h = g / (1.f + __expf(-g)) * u;
          Hout[(size_t)row * Nh + ocol0 + j * 16] = f2bf(h);
        }
      }
}

__global__ __launch_bounds__(256, 4) void k_down_all(
    const unsigned short* __restrict__ Hs,
    const unsigned short* __restrict__ Hr,
    const unsigned short* __restrict__ sWdT,
    const unsigned short* __restrict__ WdT,
    float* __restrict__ out,
    unsigned short* __restrict__ Rbuf,
    const int* __restrict__ cnt) {
  __shared__ unsigned short As[TM * BK];
  __shared__ unsigned short Bs[TND * BK];

  const int wg = xcd_swizzle();
  const int t = threadIdx.x;
  const int lane = t & 63, wv = t >> 6;
  const int lr  = lane >> 3;
  const int kbx = (lane & 7) ^ lr;

  int tm, tn, validEnd, K;
  bool routed;
  const unsigned short* pA[4];
  const unsigned short* pB[4];

  if (wg < 512) {
    routed = false; K = SHDIM;
    tm = (wg >> 3) * TM;
    tn = (wg & 7) * TND;
    validEnd = 0x7fffffff;
#pragma unroll
    for (int j = 0; j < 4; j++) {
      pA[j] = Hs + (size_t)(tm + (wv * 4 + j) * 8 + lr) * SHDIM;
      pB[j] = sWdT + (size_t)(tn + (wv * 4 + j) * 8 + lr) * SHDIM;
    }
  } else {
    routed = true; K = HDIM;
    int wgr = wg - 512;
    tm = (wgr >> 3) * TM;
    tn = (wgr & 7) * TND;
    int e, segStart, segCnt;
    if (!seg_lookup(cnt, tm, e, segStart, segCnt)) return;
    validEnd = segStart + segCnt;
    const unsigned short* B = WdT + (size_t)e * DDIM * HDIM;
#pragma unroll
    for (int j = 0; j < 4; j++) {
      pA[j] = Hr + (size_t)(tm + (wv * 4 + j) * 8 + lr) * HDIM;
      pB[j] = B + (size_t)(tn + (wv * 4 + j) * 8 + lr) * HDIM;
    }
  }

  auto stage = [&](int k0) {
#pragma unroll
    for (int j = 0; j < 4; j++) {
      gload16(pA[j] + k0 + kbx * 8, (void*)&As[(wv * 4 + j) * 512]);
      gload16(pB[j] + k0 + kbx * 8, (void*)&Bs[(wv * 4 + j) * 512]);
    }
  };

  f32x4 acc[4][4] = {};
  const int wr = wv >> 1, wc = wv & 1;
  const int rbase = lane & 15;
  const int kgrp = lane >> 4;

  for (int k0 = 0; k0 < K; k0 += BK) {
    if (k0) __syncthreads();
    stage(k0);
    __syncthreads();
#pragma unroll
    for (int kk = 0; kk < 2; kk++) {
      bf16x8 af[4], bf[4];
      int kbl = kk * 4 + kgrp;
#pragma unroll
      for (int i = 0; i < 4; i++) {
        int r = wr * 64 + i * 16 + rbase;
        af[i] = *(const bf16x8*)((const char*)&As[0] + r * 128 + ((kbl ^ (r & 7)) << 4));
      }
#pragma unroll
      for (int j = 0; j < 4; j++) {
        int r = wc * 64 + j * 16 + rbase;
        bf[j] = *(const bf16x8*)((const char*)&Bs[0] + r * 128 + ((kbl ^ (r & 7)) << 4));
      }
#pragma unroll
      for (int i = 0; i < 4; i++)
#pragma unroll
        for (int j = 0; j < 4; j++)
          acc[i][j] = __builtin_amdgcn_mfma_f32_16x16x32_bf16(af[i], bf[j], acc[i][j], 0, 0, 0);
    }
  }

  const int orow0 = tm + wr * 64 + (lane >> 4) * 4;
  const int ocol0 = tn + wc * 64 + (lane & 15);
#pragma unroll
  for (int i = 0; i < 4; i++)
#pragma unroll
    for (int j = 0; j < 4; j++)
#pragma unroll
      for (int r = 0; r < 4; r++) {
        int row = orow0 + i * 16 + r;
        int col = ocol0 + j * 16;
        if (routed) {
          if (row < validEnd) Rbuf[(size_t)row * DDIM + col] = f2bf(acc[i][j][r]);
        } else {
          out[(size_t)row * DDIM + col] = acc[i][j][r];
        }
      }
}

// out[tok] += w0 * Rbuf[r0] + w1 * Rbuf[r1]; block 0 also writes the tail
__global__ __launch_bounds__(256) void k_combine(
    float* __restrict__ out, const unsigned short* __restrict__ Rbuf,
    const int* __restrict__ tok_rows, const float* __restrict__ tok_w,
    const float* __restrict__ probsum, const int* __restrict__ cnt,
    float* __restrict__ out_tail) {
  int tok = blockIdx.x;
  int c = threadIdx.x;
  int r0 = tok_rows[tok * 2], r1 = tok_rows[tok * 2 + 1];
  float w0 = tok_w[tok * 2],  w1 = tok_w[tok * 2 + 1];
  float4 o  = ((const float4*)(out + (size_t)tok * DDIM))[c];
  ushort4 a = ((const ushort4*)(Rbuf + (size_t)r0 * DDIM))[c];
  ushort4 b = ((const ushort4*)(Rbuf + (size_t)r1 * DDIM))[c];
  o.x += w0 * bf2f(a.x) + w1 * bf2f(b.x);
  o.y += w0 * bf2f(a.y) + w1 * bf2f(b.y);
  o.z += w0 * bf2f(a.z) + w1 * bf2f(b.z);
  o.w += w0 * bf2f(a.w) + w1 * bf2f(b.w);
  ((float4*)(out + (size_t)tok * DDIM))[c] = o;

  if (blockIdx.x == 0) {
    if (threadIdx.x == 0) {
      float bal = 0.f;
      for (int e = 0; e < NEXP; e++) {
        float frac = (float)cnt[e * CPAD] / (float)(N_TOK * 2);
        bal += frac * (probsum[e * CPAD] / (float)N_TOK);
      }
      out_tail[0] = 0.01f * (float)NEXP * bal;
    }
    if (threadIdx.x < NEXP) out_tail[1 + threadIdx.x] = (float)cnt[threadIdx.x * CPAD];
  }
}

// ---------------- launch ----------------

extern "C" void kernel_launch(void* const* d_in, const int* in_sizes, int n_in,
                              void* d_out, int out_size, void* d_ws, size_t ws_size,
                              hipStream_t stream) {
  const float* x   = (const float*)d_in[0];
  const float* rw  = (const float*)d_in[1];
  const float* rb  = (const float*)d_in[2];
  const float* Wg  = (const float*)d_in[3];
  const float* Wu  = (const float*)d_in[4];
  const float* Wd  = (const float*)d_in[5];
  const float* sWg = (const float*)d_in[6];
  const float* sWu = (const float*)d_in[7];
  const float* sWd = (const float*)d_in[8];
  float* out = (float*)d_out;

  uint8_t* w = (uint8_t*)d_ws;
  size_t off = 0;
  auto alloc = [&](size_t bytes) -> void* {
    void* p = w + off;
    off += (bytes + 255) & ~(size_t)255;
    return p;
  };

  int*   cnt      = (int*)alloc(NEXP * CPAD * 4);
  int*   cursor   = (int*)alloc(NEXP * CPAD * 4);
  float* probsum  = (float*)alloc(NEXP * CPAD * 4);
  int*   tok_idx  = (int*)alloc((size_t)N_TOK * 2 * 4);
  float* tok_w    = (float*)alloc((size_t)N_TOK * 2 * 4);
  int*   tok_rows = (int*)alloc((size_t)N_TOK * 2 * 4);
  int*   row_tok  = (int*)alloc((size_t)MT_R * TM * 4);
  unsigned short* Xbf  = (unsigned short*)alloc((size_t)N_TOK * DDIM * 2);
  unsigned short* Hs   = (unsigned short*)alloc((size_t)N_TOK * SHDIM * 2);
  unsigned short* Hr   = (unsigned short*)alloc((size_t)MT_R * TM * HDIM * 2);
  unsigned short* Rbuf = (unsigned short*)alloc((size_t)MT_R * TM * DDIM * 2);
  unsigned short* WgT  = (unsigned short*)alloc((size_t)NEXP * HDIM * DDIM * 2);
  unsigned short* WuT  = (unsigned short*)alloc((size_t)NEXP * HDIM * DDIM * 2);
  unsigned short* WdT  = (unsigned short*)alloc((size_t)NEXP * DDIM * HDIM * 2);
  unsigned short* sWgT = (unsigned short*)alloc((size_t)SHDIM * DDIM * 2);
  unsigned short* sWuT = (unsigned short*)alloc((size_t)SHDIM * DDIM * 2);
  unsigned short* sWdT = (unsigned short*)alloc((size_t)DDIM * SHDIM * 2);

  if (off > ws_size) return;

  k_zero<<<1, 256, 0, stream>>>(cnt, cursor, probsum);
  k_router<<<N_TOK / 16, 256, 0, stream>>>(x, rw, rb, cnt, tok_idx, tok_w, probsum, Xbf);
  k_trgu_assign<<<T1A_WGS, 256, 0, stream>>>(
      Wg, Wu, sWg, sWu, WgT, WuT, sWgT, sWuT,
      tok_idx, cursor, cnt, row_tok, tok_rows);
  k_gateup_all<<<GUF_WGS, 256, 0, stream>>>(
      Xbf, sWgT, sWuT, WgT, WuT, Hs, Hr, cnt, row_tok,
      Wd, sWd, WdT, sWdT);
  k_down_all<<<DN_WGS, 256, 0, stream>>>(
      Hs, Hr, sWdT, WdT, out, Rbuf, cnt);
  k_combine<<<N_TOK, 256, 0, stream>>>(
      out, Rbuf, tok_rows, tok_w, probsum, cnt, out + (size_t)N_TOK * DDIM);
}

// Round 9
// 390.289 us; speedup vs baseline: 2.6191x; 1.0378x over previous
//
#include <hip/hip_runtime.h>
#include <stdint.h>

#define N_TOK 8192
#define DDIM  1024
#define NEXP  16
#define HDIM  1024
#define SHDIM 2048
#define TM 128
#define BK 64
#define MT_R 144       // max routed m-tiles: 16384 + 15*127 padded -> <= 18432 rows

// gateup merged grid (GEMM part)
#define SH_GU_NT  32
#define SH_GU_WGS 2048                 // 64 mt * 32 nt
#define RT_GU_NT  16
#define RT_GU_WGS 2304                 // 144 mt * 16 nt
#define GU_WGS    4352
#define GU_SLOTS  (GU_WGS / 8)         // 544 per XCD
// transpose riders in the gateup launch: Wd (4096 tiles) + sWd (512 tiles)
#define TR2_WGS   4608
#define TR2_SLOTS (TR2_WGS / 8)        // 576 per XCD
#define GUF_WGS   (GU_WGS + TR2_WGS)   // 8960

#define TND 128
// down grid: shared split-K (64mt*8nt*2 halves = 1024) + routed (144*8 = 1152)
#define DN_WGS    2176

// launch 3: gate/up weight transposes + assign
#define TR1_WGS   9216                 // Wg 4096 + Wu 4096 + sWg 512 + sWu 512
#define ASG_WGS   64
#define T1A_WGS   (TR1_WGS + ASG_WGS)  // 9280

#define CPAD 16   // counter padding: one 64B line per counter

typedef __bf16 bf16x8 __attribute__((ext_vector_type(8)));
typedef float  f32x4  __attribute__((ext_vector_type(4)));

__device__ __forceinline__ unsigned short f2bf(float f) {
  union { float f; unsigned u; } v; v.f = f;
  unsigned r = v.u + 0x7fffu + ((v.u >> 16) & 1u);
  return (unsigned short)(r >> 16);
}
__device__ __forceinline__ float bf2f(unsigned short u) {
  union { unsigned u; float f; } v; v.u = (unsigned)u << 16; return v.f;
}

__device__ __forceinline__ void gload16(const void* g, void* l) {
  __builtin_amdgcn_global_load_lds(
      (const __attribute__((address_space(1))) void*)g,
      (__attribute__((address_space(3))) void*)l, 16, 0, 0);
}

// XCD-aware bijective block swizzle (requires gridDim.x % 8 == 0).
__device__ __forceinline__ int xcd_swizzle() {
  int nwg = (int)gridDim.x;
  int b = (int)blockIdx.x;
  return (b & 7) * (nwg >> 3) + (b >> 3);
}

// Register-only segment lookup (NO local array -> no scratch, rule #20).
__device__ __forceinline__ bool seg_lookup(const int* __restrict__ cnt, int tm,
                                           int& e, int& segStart, int& segCnt) {
  int o = 0; e = 0; segStart = 0; segCnt = 0;
#pragma unroll
  for (int i = 0; i < NEXP; i++) {
    int c = cnt[i * CPAD];
    if (tm >= o) { e = i; segStart = o; segCnt = c; }
    o += (c + 127) & ~127;
  }
  return tm < o;
}

// ---------------- small setup kernels ----------------

__global__ void k_zero(int* cnt, int* cursor, float* probsum) {
  int t = threadIdx.x;
  if (t < NEXP * CPAD) { cnt[t] = 0; cursor[t] = 0; probsum[t] = 0.f; }
}

// 512 blocks x 256 threads; 16 tokens/block (4 per wave).
// Emits Xbf, top-2 routing, cnt atomics, and block-reduced probsum.
__global__ __launch_bounds__(256) void k_router(
    const float* __restrict__ x, const float* __restrict__ rw,
    const float* __restrict__ rb, int* __restrict__ cnt,
    int* __restrict__ tok_idx, float* __restrict__ tok_w,
    float* __restrict__ probsum, unsigned short* __restrict__ Xbf) {
  __shared__ float rwT[NEXP * 1024];
  __shared__ float ps[NEXP];
  const int t = threadIdx.x;
  if (t < NEXP) ps[t] = 0.f;
  {
    int dbase = t >> 2, e0 = (t & 3) * 4;
#pragma unroll
    for (int c = 0; c < 16; c++) {
      int d = dbase + 64 * c;
      float4 v = *(const float4*)(rw + (size_t)d * NEXP + e0);
      rwT[(e0 + 0) * 1024 + d] = v.x;
      rwT[(e0 + 1) * 1024 + d] = v.y;
      rwT[(e0 + 2) * 1024 + d] = v.z;
      rwT[(e0 + 3) * 1024 + d] = v.w;
    }
  }
  __syncthreads();
  const int lane = t & 63, wv = t >> 6;
  const int tok0 = blockIdx.x * 16 + wv * 4;
  float acc[4][NEXP];
#pragma unroll
  for (int tt = 0; tt < 4; tt++)
#pragma unroll
    for (int e = 0; e < NEXP; e++) acc[tt][e] = 0.f;

#pragma unroll
  for (int c = 0; c < 4; c++) {
    int d = lane * 4 + 256 * c;
    float4 xv[4];
#pragma unroll
    for (int tt = 0; tt < 4; tt++) {
      xv[tt] = *(const float4*)(x + (size_t)(tok0 + tt) * DDIM + d);
      ushort4 o;
      o.x = f2bf(xv[tt].x); o.y = f2bf(xv[tt].y);
      o.z = f2bf(xv[tt].z); o.w = f2bf(xv[tt].w);
      *(ushort4*)(Xbf + (size_t)(tok0 + tt) * DDIM + d) = o;
    }
#pragma unroll
    for (int e = 0; e < NEXP; e++) {
      float4 w4 = *(const float4*)(&rwT[e * 1024 + d]);
#pragma unroll
      for (int tt = 0; tt < 4; tt++) {
        acc[tt][e] = fmaf(xv[tt].x, w4.x, acc[tt][e]);
        acc[tt][e] = fmaf(xv[tt].y, w4.y, acc[tt][e]);
        acc[tt][e] = fmaf(xv[tt].z, w4.z, acc[tt][e]);
        acc[tt][e] = fmaf(xv[tt].w, w4.w, acc[tt][e]);
      }
    }
  }
#pragma unroll
  for (int tt = 0; tt < 4; tt++)
#pragma unroll
    for (int e = 0; e < NEXP; e++) {
      float v = acc[tt][e];
#pragma unroll
      for (int o = 32; o; o >>= 1) v += __shfl_xor(v, o);
      acc[tt][e] = v;
    }

#pragma unroll
  for (int tt = 0; tt < 4; tt++) {
    if (lane == tt) {
      int tok = tok0 + tt;
      float mx = acc[tt][0];
#pragma unroll
      for (int e = 1; e < NEXP; e++) mx = fmaxf(mx, acc[tt][e]);
      float p[NEXP]; float s = 0.f;
#pragma unroll
      for (int e = 0; e < NEXP; e++) { p[e] = __expf(acc[tt][e] - mx); s += p[e]; }
      float inv = 1.f / s;
#pragma unroll
      for (int e = 0; e < NEXP; e++) { p[e] *= inv; atomicAdd(&ps[e], p[e]); }
      int i0 = 0; float b0 = acc[tt][0] + rb[0];
#pragma unroll
      for (int e = 1; e < NEXP; e++) { float v = acc[tt][e] + rb[e]; if (v > b0) { b0 = v; i0 = e; } }
      int i1 = -1; float b1 = -3.4e38f;
#pragma unroll
      for (int e = 0; e < NEXP; e++) {
        if (e == i0) continue;
        float v = acc[tt][e] + rb[e]; if (v > b1) { b1 = v; i1 = e; }
      }
      float w0 = 0.f, w1 = 0.f;
#pragma unroll
      for (int e = 0; e < NEXP; e++) { if (e == i0) w0 = p[e]; if (e == i1) w1 = p[e]; }
      float ssum = fmaxf(w0 + w1, 1e-9f);
      w0 /= ssum; w1 /= ssum;
      atomicAdd(&cnt[i0 * CPAD], 1); atomicAdd(&cnt[i1 * CPAD], 1);
      tok_idx[tok * 2]     = i0; tok_idx[tok * 2 + 1] = i1;
      tok_w[tok * 2]       = w0; tok_w[tok * 2 + 1]   = w1;
    }
  }
  __syncthreads();
  if (t < NEXP) atomicAdd(&probsum[t * CPAD], ps[t]);
}

// ---------------- transpose helper (fp32 [R][C] -> bf16 [C][R]) ----------------

__device__ __forceinline__ void do_transpose64(
    const float* __restrict__ src, unsigned short* __restrict__ dst,
    int R, int C, int tc, int tr, float* tile /* 64*65 */) {
  int rx = threadIdx.x >> 4;
  int cx = (threadIdx.x & 15) * 4;
#pragma unroll
  for (int p = 0; p < 4; p++) {
    int r = p * 16 + rx;
    float4 v = *(const float4*)(src + (size_t)(tr + r) * C + tc + cx);
    tile[(cx + 0) * 65 + r] = v.x;
    tile[(cx + 1) * 65 + r] = v.y;
    tile[(cx + 2) * 65 + r] = v.z;
    tile[(cx + 3) * 65 + r] = v.w;
  }
  __syncthreads();
#pragma unroll
  for (int p = 0; p < 4; p++) {
    int c = p * 16 + rx;
    float v0 = tile[c * 65 + cx + 0];
    float v1 = tile[c * 65 + cx + 1];
    float v2 = tile[c * 65 + cx + 2];
    float v3 = tile[c * 65 + cx + 3];
    ushort4 o; o.x = f2bf(v0); o.y = f2bf(v1); o.z = f2bf(v2); o.w = f2bf(v3);
    *(ushort4*)(dst + (size_t)(tc + c) * R + tr + cx) = o;
  }
}

// launch 3: gate/up weight transposes (9216 blocks) + routed-row assign (64 blocks)
__global__ __launch_bounds__(256) void k_trgu_assign(
    const float* __restrict__ Wg, const float* __restrict__ Wu,
    const float* __restrict__ sWg, const float* __restrict__ sWu,
    unsigned short* __restrict__ WgT, unsigned short* __restrict__ WuT,
    unsigned short* __restrict__ sWgT, unsigned short* __restrict__ sWuT,
    const int* __restrict__ tok_idx, int* __restrict__ cursor,
    const int* __restrict__ cnt, int* __restrict__ row_token,
    int* __restrict__ tok_rows) {
  __shared__ float tile[64 * 65];
  int id = blockIdx.x;
  if (id < 4096) {
    int mat = id >> 8, tl = id & 255;
    do_transpose64(Wg + ((size_t)mat << 20), WgT + ((size_t)mat << 20),
                   1024, 1024, (tl & 15) * 64, (tl >> 4) * 64, tile);
  } else if (id < 8192) {
    int mat = (id - 4096) >> 8, tl = id & 255;
    do_transpose64(Wu + ((size_t)mat << 20), WuT + ((size_t)mat << 20),
                   1024, 1024, (tl & 15) * 64, (tl >> 4) * 64, tile);
  } else if (id < 8704) {
    int tl = id - 8192;
    do_transpose64(sWg, sWgT, 1024, 2048, (tl & 31) * 64, (tl >> 5) * 64, tile);
  } else if (id < TR1_WGS) {
    int tl = id - 8704;
    do_transpose64(sWu, sWuT, 1024, 2048, (tl & 31) * 64, (tl >> 5) * 64, tile);
  } else {
    int i = (id - TR1_WGS) * 256 + threadIdx.x;   // [0, 16384)
    int e = tok_idx[i];
    // register-only offs[e]: scan with per-step compare (no local array)
    int o = 0, myoff = 0;
#pragma unroll
    for (int k = 0; k < NEXP; k++) {
      if (e == k) myoff = o;
      o += (cnt[k * CPAD] + 127) & ~127;
    }
    int pos = atomicAdd(&cursor[e * CPAD], 1);
    int row = myoff + pos;
    row_token[row] = i >> 1;
    tok_rows[i] = row;
  }
}

// ---------------- merged GEMM kernels (m97 structure) ----------------
// Single-buffered 32KB LDS, 2-barrier K-loop, global_load_lds width 16,
// 16B-unit XOR swizzle, per-XCD slot split: GEMM slots first (banded tile
// order), then Wd/sWd transpose riders that soak idle HBM BW.
// __launch_bounds__(256,4): cap=128 VGPR/wave fits 64 arch + 64 acc exactly;
// (256,5) capped at ~96 and spilled the accumulators (round-6 regression).

__global__ __launch_bounds__(256, 4) void k_gateup_all(
    const unsigned short* __restrict__ Xbf,
    const unsigned short* __restrict__ sWgT,
    const unsigned short* __restrict__ sWuT,
    const unsigned short* __restrict__ WgT,
    const unsigned short* __restrict__ WuT,
    unsigned short* __restrict__ Hs,
    unsigned short* __restrict__ Hr,
    const int* __restrict__ cnt,
    const int* __restrict__ row_token,
    const float* __restrict__ Wd, const float* __restrict__ sWd,
    unsigned short* __restrict__ WdT, unsigned short* __restrict__ sWdT) {
  __shared__ __attribute__((aligned(16))) char smem[32768];
  unsigned short* As  = (unsigned short*)smem;             // 16 KB
  unsigned short* Bgs = (unsigned short*)(smem + 16384);   //  8 KB
  unsigned short* Bus = (unsigned short*)(smem + 24576);   //  8 KB

  const int slot = blockIdx.x >> 3;
  const int xcd  = blockIdx.x & 7;

  if (slot >= GU_SLOTS) {
    // transpose riders: Wd (4096 tiles) then sWd (512)
    int tid = xcd * TR2_SLOTS + (slot - GU_SLOTS);
    float* tile = (float*)smem;
    if (tid < 4096) {
      int mat = tid >> 8, tl = tid & 255;
      do_transpose64(Wd + ((size_t)mat << 20), WdT + ((size_t)mat << 20),
                     1024, 1024, (tl & 15) * 64, (tl >> 4) * 64, tile);
    } else {
      int tl = tid - 4096;
      do_transpose64(sWd, sWdT, 2048, 1024, (tl & 15) * 64, (tl >> 4) * 64, tile);
    }
    return;
  }

  const int wg = xcd * GU_SLOTS + slot;   // [0, 4352), contiguous per XCD
  const int t = threadIdx.x;
  const int lane = t & 63, wv = t >> 6;
  const int lr  = lane >> 3;            // row within 8-row chunk
  const int kbx = (lane & 7) ^ lr;      // pre-swizzled 16B-unit column

  int tm, tn, validEnd, Nh;
  const unsigned short *Bgp, *Bup;
  unsigned short* Hout;
  const unsigned short* pA[4];

  if (wg < SH_GU_WGS) {
    // banded decode: band of 8 nt, mt fastest inside
    int band = wg >> 9;
    int r = wg & 511;
    tm = (r >> 3) * TM;
    tn = (band * 8 + (r & 7)) * 64;
    validEnd = 0x7fffffff;
    Bgp = sWgT; Bup = sWuT;
    Hout = Hs; Nh = SHDIM;
#pragma unroll
    for (int j = 0; j < 4; j++)
      pA[j] = Xbf + (size_t)(tm + (wv * 4 + j) * 8 + lr) * DDIM;
  } else {
    int u = wg - SH_GU_WGS;
    int band = u / 1152;
    int r = u % 1152;
    tm = (r >> 3) * TM;
    tn = (band * 8 + (r & 7)) * 64;
    int e, segStart, segCnt;
    if (!seg_lookup(cnt, tm, e, segStart, segCnt)) return;
    validEnd = segStart + segCnt;
    Bgp = WgT + (size_t)e * HDIM * DDIM;
    Bup = WuT + (size_t)e * HDIM * DDIM;
    Hout = Hr; Nh = HDIM;
#pragma unroll
    for (int j = 0; j < 4; j++) {
      int row = tm + (wv * 4 + j) * 8 + lr;
      int tok = row < validEnd ? row_token[row] : 0;
      pA[j] = Xbf + (size_t)tok * DDIM;
    }
  }
  const unsigned short* pBg[2];
  const unsigned short* pBu[2];
#pragma unroll
  for (int j = 0; j < 2; j++) {
    int row = tn + (wv * 2 + j) * 8 + lr;
    pBg[j] = Bgp + (size_t)row * DDIM;
    pBu[j] = Bup + (size_t)row * DDIM;
  }

  auto stage = [&](int k0) {
#pragma unroll
    for (int j = 0; j < 4; j++)
      gload16(pA[j] + k0 + kbx * 8, (void*)&As[(wv * 4 + j) * 512]);
#pragma unroll
    for (int j = 0; j < 2; j++) {
      gload16(pBg[j] + k0 + kbx * 8, (void*)&Bgs[(wv * 2 + j) * 512]);
      gload16(pBu[j] + k0 + kbx * 8, (void*)&Bus[(wv * 2 + j) * 512]);
    }
  };

  f32x4 accG[4][2] = {};
  f32x4 accU[4][2] = {};
  const int wr = wv >> 1, wc = wv & 1;
  const int rbase = lane & 15;
  const int kgrp = lane >> 4;

  for (int k0 = 0; k0 < DDIM; k0 += BK) {
    if (k0) __syncthreads();
    stage(k0);
    __syncthreads();
#pragma unroll
    for (int kk = 0; kk < 2; kk++) {
      bf16x8 af[4], gf[2], uf[2];
      int kbl = kk * 4 + kgrp;
#pragma unroll
      for (int i = 0; i < 4; i++) {
        int r = wr * 64 + i * 16 + rbase;
        af[i] = *(const bf16x8*)((const char*)As + r * 128 + ((kbl ^ (r & 7)) << 4));
      }
#pragma unroll
      for (int j = 0; j < 2; j++) {
        int r = wc * 32 + j * 16 + rbase;
        gf[j] = *(const bf16x8*)((const char*)Bgs + r * 128 + ((kbl ^ (r & 7)) << 4));
        uf[j] = *(const bf16x8*)((const char*)Bus + r * 128 + ((kbl ^ (r & 7)) << 4));
      }
#pragma unroll
      for (int i = 0; i < 4; i++)
#pragma unroll
        for (int j = 0; j < 2; j++) {
          accG[i][j] = __builtin_amdgcn_mfma_f32_16x16x32_bf16(af[i], gf[j], accG[i][j], 0, 0, 0);
          accU[i][j] = __builtin_amdgcn_mfma_f32_16x16x32_bf16(af[i], uf[j], accU[i][j], 0, 0, 0);
        }
    }
  }

  const int orow0 = tm + wr * 64 + (lane >> 4) * 4;
  const int ocol0 = tn + wc * 32 + (lane & 15);
#pragma unroll
  for (int i = 0; i < 4; i++)
#pragma unroll
    for (int j = 0; j < 2; j++)
#pragma unroll
      for (int r = 0; r < 4; r++) {
        int row = orow0 + i * 16 + r;
        if (row < validEnd) {
          float g = accG[i][j][r], u = accU[i][j][r];
          float h = g / (1.f + __expf(-g)) * u;
          Hout[(size_t)row * Nh + ocol0 + j * 16] = f2bf(h);
        }
      }
}

// down: all blocks uniform K=1024. Shared segment is split-K: half 0 stores
// fp32 out, half 1 stores fp32 Pbuf partial; routed stores bf16 Rbuf rows.
__global__ __launch_bounds__(256, 4) void k_down_all(
    const unsigned short* __restrict__ Hs,
    const unsigned short* __restrict__ Hr,
    const unsigned short* __restrict__ sWdT,
    const unsigned short* __restrict__ WdT,
    float* __restrict__ out,
    float* __restrict__ Pbuf,
    unsigned short* __restrict__ Rbuf,
    const int* __restrict__ cnt) {
  __shared__ unsigned short As[TM * BK];
  __shared__ unsigned short Bs[TND * BK];

  const int wg = xcd_swizzle();
  const int t = threadIdx.x;
  const int lane = t & 63, wv = t >> 6;
  const int lr  = lane >> 3;
  const int kbx = (lane & 7) ^ lr;

  int tm, tn, validEnd;
  bool routed;
  float* outF = out;
  const unsigned short* pA[4];
  const unsigned short* pB[4];

  if (wg < 1024) {
    routed = false;
    int half = wg >> 9;          // 0 or 1 -> K range [half*1024, half*1024+1024)
    int r = wg & 511;
    tm = (r >> 3) * TM;
    tn = (r & 7) * TND;
    validEnd = 0x7fffffff;
    outF = half ? Pbuf : out;
    int kbase = half << 10;
#pragma unroll
    for (int j = 0; j < 4; j++) {
      pA[j] = Hs + (size_t)(tm + (wv * 4 + j) * 8 + lr) * SHDIM + kbase;
      pB[j] = sWdT + (size_t)(tn + (wv * 4 + j) * 8 + lr) * SHDIM + kbase;
    }
  } else {
    routed = true;
    int wgr = wg - 1024;
    tm = (wgr >> 3) * TM;
    tn = (wgr & 7) * TND;
    int e, segStart, segCnt;
    if (!seg_lookup(cnt, tm, e, segStart, segCnt)) return;
    validEnd = segStart + segCnt;
    const unsigned short* B = WdT + (size_t)e * DDIM * HDIM;
#pragma unroll
    for (int j = 0; j < 4; j++) {
      pA[j] = Hr + (size_t)(tm + (wv * 4 + j) * 8 + lr) * HDIM;
      pB[j] = B + (size_t)(tn + (wv * 4 + j) * 8 + lr) * HDIM;
    }
  }

  auto stage = [&](int k0) {
#pragma unroll
    for (int j = 0; j < 4; j++) {
      gload16(pA[j] + k0 + kbx * 8, (void*)&As[(wv * 4 + j) * 512]);
      gload16(pB[j] + k0 + kbx * 8, (void*)&Bs[(wv * 4 + j) * 512]);
    }
  };

  f32x4 acc[4][4] = {};
  const int wr = wv >> 1, wc = wv & 1;
  const int rbase = lane & 15;
  const int kgrp = lane >> 4;

  for (int k0 = 0; k0 < 1024; k0 += BK) {
    if (k0) __syncthreads();
    stage(k0);
    __syncthreads();
#pragma unroll
    for (int kk = 0; kk < 2; kk++) {
      bf16x8 af[4], bf[4];
      int kbl = kk * 4 + kgrp;
#pragma unroll
      for (int i = 0; i < 4; i++) {
        int r = wr * 64 + i * 16 + rbase;
        af[i] = *(const bf16x8*)((const char*)&As[0] + r * 128 + ((kbl ^ (r & 7)) << 4));
      }
#pragma unroll
      for (int j = 0; j < 4; j++) {
        int r = wc * 64 + j * 16 + rbase;
        bf[j] = *(const bf16x8*)((const char*)&Bs[0] + r * 128 + ((kbl ^ (r & 7)) << 4));
      }
#pragma unroll
      for (int i = 0; i < 4; i++)
#pragma unroll
        for (int j = 0; j < 4; j++)
          acc[i][j] = __builtin_amdgcn_mfma_f32_16x16x32_bf16(af[i], bf[j], acc[i][j], 0, 0, 0);
    }
  }

  const int orow0 = tm + wr * 64 + (lane >> 4) * 4;
  const int ocol0 = tn + wc * 64 + (lane & 15);
#pragma unroll
  for (int i = 0; i < 4; i++)
#pragma unroll
    for (int j = 0; j < 4; j++)
#pragma unroll
      for (int r = 0; r < 4; r++) {
        int row = orow0 + i * 16 + r;
        int col = ocol0 + j * 16;
        if (routed) {
          if (row < validEnd) Rbuf[(size_t)row * DDIM + col] = f2bf(acc[i][j][r]);
        } else {
          outF[(size_t)row * DDIM + col] = acc[i][j][r];
        }
      }
}

// out[tok] = out[tok] + Pbuf[tok] + w0 * Rbuf[r0] + w1 * Rbuf[r1]
// block 0 also writes the tail (balance + expert_load)
__global__ __launch_bounds__(256) void k_combine(
    float* __restrict__ out, const float* __restrict__ Pbuf,
    const unsigned short* __restrict__ Rbuf,
    const int* __restrict__ tok_rows, const float* __restrict__ tok_w,
    const float* __restrict__ probsum, const int* __restrict__ cnt,
    float* __restrict__ out_tail) {
  int tok = blockIdx.x;
  int c = threadIdx.x;
  int r0 = tok_rows[tok * 2], r1 = tok_rows[tok * 2 + 1];
  float w0 = tok_w[tok * 2],  w1 = tok_w[tok * 2 + 1];
  float4 o  = ((const float4*)(out + (size_t)tok * DDIM))[c];
  float4 p  = ((const float4*)(Pbuf + (size_t)tok * DDIM))[c];
  ushort4 a = ((const ushort4*)(Rbuf + (size_t)r0 * DDIM))[c];
  ushort4 b = ((const ushort4*)(Rbuf + (size_t)r1 * DDIM))[c];
  o.x += p.x + w0 * bf2f(a.x) + w1 * bf2f(b.x);
  o.y += p.y + w0 * bf2f(a.y) + w1 * bf2f(b.y);
  o.z += p.z + w0 * bf2f(a.z) + w1 * bf2f(b.z);
  o.w += p.w + w0 * bf2f(a.w) + w1 * bf2f(b.w);
  ((float4*)(out + (size_t)tok * DDIM))[c] = o;

  if (blockIdx.x == 0) {
    if (threadIdx.x == 0) {
      float bal = 0.f;
      for (int e = 0; e < NEXP; e++) {
        float frac = (float)cnt[e * CPAD] / (float)(N_TOK * 2);
        bal += frac * (probsum[e * CPAD] / (float)N_TOK);
      }
      out_tail[0] = 0.01f * (float)NEXP * bal;
    }
    if (threadIdx.x < NEXP) out_tail[1 + threadIdx.x] = (float)cnt[threadIdx.x * CPAD];
  }
}

// ---------------- launch ----------------

extern "C" void kernel_launch(void* const* d_in, const int* in_sizes, int n_in,
                              void* d_out, int out_size, void* d_ws, size_t ws_size,
                              hipStream_t stream) {
  const float* x   = (const float*)d_in[0];
  const float* rw  = (const float*)d_in[1];
  const float* rb  = (const float*)d_in[2];
  const float* Wg  = (const float*)d_in[3];
  const float* Wu  = (const float*)d_in[4];
  const float* Wd  = (const float*)d_in[5];
  const float* sWg = (const float*)d_in[6];
  const float* sWu = (const float*)d_in[7];
  const float* sWd = (const float*)d_in[8];
  float* out = (float*)d_out;

  uint8_t* w = (uint8_t*)d_ws;
  size_t off = 0;
  auto alloc = [&](size_t bytes) -> void* {
    void* p = w + off;
    off += (bytes + 255) & ~(size_t)255;
    return p;
  };

  int*   cnt      = (int*)alloc(NEXP * CPAD * 4);
  int*   cursor   = (int*)alloc(NEXP * CPAD * 4);
  float* probsum  = (float*)alloc(NEXP * CPAD * 4);
  int*   tok_idx  = (int*)alloc((size_t)N_TOK * 2 * 4);
  float* tok_w    = (float*)alloc((size_t)N_TOK * 2 * 4);
  int*   tok_rows = (int*)alloc((size_t)N_TOK * 2 * 4);
  int*   row_tok  = (int*)alloc((size_t)MT_R * TM * 4);
  unsigned short* Xbf  = (unsigned short*)alloc((size_t)N_TOK * DDIM * 2);
  unsigned short* Hs   = (unsigned short*)alloc((size_t)N_TOK * SHDIM * 2);
  unsigned short* Hr   = (unsigned short*)alloc((size_t)MT_R * TM * HDIM * 2);
  unsigned short* Rbuf = (unsigned short*)alloc((size_t)MT_R * TM * DDIM * 2);
  unsigned short* WgT  = (unsigned short*)alloc((size_t)NEXP * HDIM * DDIM * 2);
  unsigned short* WuT  = (unsigned short*)alloc((size_t)NEXP * HDIM * DDIM * 2);
  unsigned short* WdT  = (unsigned short*)alloc((size_t)NEXP * DDIM * HDIM * 2);
  unsigned short* sWgT = (unsigned short*)alloc((size_t)SHDIM * DDIM * 2);
  unsigned short* sWuT = (unsigned short*)alloc((size_t)SHDIM * DDIM * 2);
  unsigned short* sWdT = (unsigned short*)alloc((size_t)DDIM * SHDIM * 2);

  // Pbuf (32 MiB fp32) ALIASES WgT (32 MiB bf16): WgT's last reader is
  // k_gateup_all; k_down_all (Pbuf's writer) runs strictly after it.
  // Avoids exceeding ws_size (round-8 failure: +32MB overflowed workspace).
  float* Pbuf = (float*)WgT;

  if (off > ws_size) return;

  k_zero<<<1, 256, 0, stream>>>(cnt, cursor, probsum);
  k_router<<<N_TOK / 16, 256, 0, stream>>>(x, rw, rb, cnt, tok_idx, tok_w, probsum, Xbf);
  k_trgu_assign<<<T1A_WGS, 256, 0, stream>>>(
      Wg, Wu, sWg, sWu, WgT, WuT, sWgT, sWuT,
      tok_idx, cursor, cnt, row_tok, tok_rows);
  k_gateup_all<<<GUF_WGS, 256, 0, stream>>>(
      Xbf, sWgT, sWuT, WgT, WuT, Hs, Hr, cnt, row_tok,
      Wd, sWd, WdT, sWdT);
  k_down_all<<<DN_WGS, 256, 0, stream>>>(
      Hs, Hr, sWdT, WdT, out, Pbuf, Rbuf, cnt);
  k_combine<<<N_TOK, 256, 0, stream>>>(
      out, Pbuf, Rbuf, tok_rows, tok_w, probsum, cnt, out + (size_t)N_TOK * DDIM);
}